// Round 3
// baseline (506.068 us; speedup 1.0000x reference)
//
#include <hip/hip_runtime.h>
#include <hip/hip_bf16.h>

typedef unsigned int uint;
typedef unsigned short ushort;
typedef float v2f __attribute__((ext_vector_type(2)));

#define NATOMS 20000
#define NEDGES 640000
#define FD 128
#define F3 384
#define NR 20
#define GAPB 2      // atoms per block, gather
#define PREP_BLOCKS ((NEDGES + 255) / 256)   // 2500
#define MLP_BLOCKS  (NATOMS / 32)            // 625 (32 atoms per block)

__device__ __forceinline__ uint f2bfu(float f) {   // f32 -> bf16 bits, RNE
  const uint u = __float_as_uint(f);
  return (u + 0x7FFFu + ((u >> 16) & 1u)) >> 16;
}
__device__ __forceinline__ float bflo(uint u) { return __uint_as_float(u << 16); }
__device__ __forceinline__ float bfhi(uint u) { return __uint_as_float(u & 0xFFFF0000u); }

// ---------------------------------------------------------------------------
// CSR build: histogram -> exclusive scan (writes off AND cursor).
// ---------------------------------------------------------------------------
__global__ __launch_bounds__(256) void hist_kernel(const int* __restrict__ eidx,
                                                   int* __restrict__ cnt) {
  const int e = blockIdx.x * 256 + threadIdx.x;
  if (e < NEDGES) atomicAdd(&cnt[eidx[e]], 1);
}

__global__ __launch_bounds__(512) void scan_kernel(const int* __restrict__ cnt,
                                                   int* __restrict__ off,
                                                   int* __restrict__ cursor) {
  __shared__ int part[512];
  const int t = threadIdx.x;
  const int CH = (NATOMS + 511) / 512;
  const int base = t * CH;
  int s = 0;
  for (int k = 0; k < CH; ++k) {
    const int idx = base + k;
    if (idx < NATOMS) s += cnt[idx];
  }
  part[t] = s;
  __syncthreads();
  if (t == 0) {
    int run = 0;
    for (int i = 0; i < 512; ++i) { const int tmp = part[i]; part[i] = run; run += tmp; }
    off[NATOMS] = run;
  }
  __syncthreads();
  int run = part[t];
  for (int k = 0; k < CH; ++k) {
    const int idx = base + k;
    if (idx < NATOMS) { off[idx] = run; cursor[idx] = run; run += cnt[idx]; }
  }
}

// ---------------------------------------------------------------------------
// Fused prep | mlp (block-range specialization; the two are independent and
// previously serialized on the stream -- overlap saves min(prep, mlp)).
//
// prep (blocks [0, PREP_BLOCKS)): 32B basis record at destination-sorted
//   position. rec: [0] v0=sin(th)*env/d [1] 2cos(th) [2] env [3..5] dir [6] j.
//
// mlp (blocks [PREP_BLOCKS, PREP_BLOCKS+MLP_BLOCKS)): 256 threads = two
//   independent 128-thread halves, 16 atoms each. K-loops quad-unrolled with
//   float4 LDS broadcasts: 4x fewer LDS instructions than the b32 version
//   (which was ~95us LDS-issue-bound: 4096 ds_read_b32/wave * 2500 waves).
//   Packs per (atom,feature t) a 12B record [x0|x1, x2|m0, m1|m2] bf16.
// ---------------------------------------------------------------------------
__global__ __launch_bounds__(256, 4) void prep_mlp_kernel(
    const int* __restrict__ eidx, const float* __restrict__ ew,
    int* __restrict__ cursor, uint4* __restrict__ basisS,
    const float* __restrict__ q, const float* __restrict__ mu,
    const float* __restrict__ W1, const float* __restrict__ b1,
    const float* __restrict__ W2, const float* __restrict__ b2v,
    uint* __restrict__ xmp)
{
  __shared__ float qL[2][16][FD];   // 16 KB
  __shared__ float hL[2][16][FD];   // 16 KB

  const int t = threadIdx.x;

  if (blockIdx.x < PREP_BLOCKS) {
    // ------------------------------ prep ------------------------------
    const int e = blockIdx.x * 256 + t;
    if (e >= NEDGES) return;
    const int i = eidx[e];
    const int j = eidx[NEDGES + e];
    const int pos = atomicAdd(&cursor[i], 1);

    const float w0 = ew[(size_t)e * 3 + 0];
    const float w1 = ew[(size_t)e * 3 + 1];
    const float w2 = ew[(size_t)e * 3 + 2];
    const float d = sqrtf(w0 * w0 + w1 * w1 + w2 * w2);
    const float invd = 1.f / d;
    float s1, c1;
    __sincosf(d * 0.628318530717958f, &s1, &c1);   // theta = pi*d/5
    const float env = (d < 5.f) ? 0.5f * (c1 + 1.f) : 0.f;

    uint4 r0, r1;
    r0.x = __float_as_uint(s1 * env * invd);
    r0.y = __float_as_uint(2.f * c1);
    r0.z = __float_as_uint(env);
    r0.w = __float_as_uint(w0 * invd);
    r1.x = __float_as_uint(w1 * invd);
    r1.y = __float_as_uint(w2 * invd);
    r1.z = (uint)j;
    r1.w = 0u;
    basisS[(size_t)pos * 2 + 0] = r0;
    basisS[(size_t)pos * 2 + 1] = r1;
    return;
  }

  // ------------------------------- mlp --------------------------------
  const int half = t >> 7;          // two independent 128-thread halves
  const int tc = t & 127;
  const int a0 = (blockIdx.x - PREP_BLOCKS) * 32 + half * 16;

  #pragma unroll
  for (int a = 0; a < 16; ++a) qL[half][a][tc] = q[(size_t)(a0 + a) * FD + tc];
  __syncthreads();

  float hacc[16];
  const float bb1 = b1[tc];
  #pragma unroll
  for (int a = 0; a < 16; ++a) hacc[a] = bb1;
  for (int i = 0; i < FD; i += 4) {
    const float w0 = W1[(size_t)i * FD + tc];
    const float w1 = W1[(size_t)(i + 1) * FD + tc];
    const float w2 = W1[(size_t)(i + 2) * FD + tc];
    const float w3 = W1[(size_t)(i + 3) * FD + tc];
    #pragma unroll
    for (int a = 0; a < 16; ++a) {
      const float4 qv = *(const float4*)&qL[half][a][i];   // b128 broadcast
      hacc[a] += qv.x * w0 + qv.y * w1 + qv.z * w2 + qv.w * w3;
    }
  }
  #pragma unroll
  for (int a = 0; a < 16; ++a) hL[half][a][tc] = hacc[a] / (1.f + __expf(-hacc[a]));
  __syncthreads();

  float x0[16], x1[16], x2[16];
  const float c0 = b2v[tc], c1 = b2v[FD + tc], c2 = b2v[2 * FD + tc];
  #pragma unroll
  for (int a = 0; a < 16; ++a) { x0[a] = c0; x1[a] = c1; x2[a] = c2; }
  for (int i = 0; i < FD; i += 4) {
    const float wa0 = W2[(size_t)i * F3 + tc];
    const float wa1 = W2[(size_t)(i + 1) * F3 + tc];
    const float wa2 = W2[(size_t)(i + 2) * F3 + tc];
    const float wa3 = W2[(size_t)(i + 3) * F3 + tc];
    const float wb0 = W2[(size_t)i * F3 + FD + tc];
    const float wb1 = W2[(size_t)(i + 1) * F3 + FD + tc];
    const float wb2 = W2[(size_t)(i + 2) * F3 + FD + tc];
    const float wb3 = W2[(size_t)(i + 3) * F3 + FD + tc];
    const float wc0 = W2[(size_t)i * F3 + 2 * FD + tc];
    const float wc1 = W2[(size_t)(i + 1) * F3 + 2 * FD + tc];
    const float wc2 = W2[(size_t)(i + 2) * F3 + 2 * FD + tc];
    const float wc3 = W2[(size_t)(i + 3) * F3 + 2 * FD + tc];
    #pragma unroll
    for (int a = 0; a < 16; ++a) {
      const float4 hv = *(const float4*)&hL[half][a][i];   // b128 broadcast
      x0[a] += hv.x * wa0 + hv.y * wa1 + hv.z * wa2 + hv.w * wa3;
      x1[a] += hv.x * wb0 + hv.y * wb1 + hv.z * wb2 + hv.w * wb3;
      x2[a] += hv.x * wc0 + hv.y * wc1 + hv.z * wc2 + hv.w * wc3;
    }
  }
  #pragma unroll
  for (int a = 0; a < 16; ++a) {
    const int n = a0 + a;
    const float* ma = mu + (size_t)n * F3;
    const float m0 = ma[tc], m1 = ma[FD + tc], m2 = ma[2 * FD + tc];
    uint* dst = xmp + ((size_t)n * FD + tc) * 3;
    dst[0] = f2bfu(x0[a]) | (f2bfu(x1[a]) << 16);
    dst[1] = f2bfu(x2[a]) | (f2bfu(m0) << 16);
    dst[2] = f2bfu(m1)    | (f2bfu(m2) << 16);
  }
}

// ---------------------------------------------------------------------------
// Phase 2: 128-thread blocks, GAPB=2 atoms each (contiguous CSR range).
// Thread t owns filter columns {t, 128+t, 256+t} -> the 6 b128 basis
// broadcasts per edge are amortized over all 3 columns.
// __launch_bounds__(128,3): VGPR cap ~170 so the 60-VGPR Wf slice stays
// register-resident. Depth-2 prefetch with NAMED scalars.
// (UNCHANGED from round 2 -- 212us, VALUBusy 74%.)
// ---------------------------------------------------------------------------
__global__ __launch_bounds__(128, 3) void gather_kernel(
    const float* __restrict__ q, const float* __restrict__ mu,
    const uint* __restrict__ xmp,
    const float* __restrict__ Wf, const float* __restrict__ bfv,
    const int* __restrict__ off, const uint* __restrict__ basisS,
    float* __restrict__ out)
{
  __shared__ uint stage[64 * 8];   // raw 32B records
  __shared__ float fb[64][28];     // [0..19] basis f32, [20..23] env+dir, [24] j
  const int t = threadIdx.x;
  const int a0 = blockIdx.x * GAPB;

  v2f wf0[10], wf1[10], wf2[10];
  #pragma unroll
  for (int r = 0; r < 10; ++r) {
    wf0[r] = (v2f){Wf[(size_t)(2 * r) * F3 + t],       Wf[(size_t)(2 * r + 1) * F3 + t]};
    wf1[r] = (v2f){Wf[(size_t)(2 * r) * F3 + 128 + t], Wf[(size_t)(2 * r + 1) * F3 + 128 + t]};
    wf2[r] = (v2f){Wf[(size_t)(2 * r) * F3 + 256 + t], Wf[(size_t)(2 * r + 1) * F3 + 256 + t]};
  }
  const float bias0 = bfv[t], bias1 = bfv[128 + t], bias2 = bfv[256 + t];

  int a = a0;
  const int beg  = off[a0];
  const int pEnd = off[a0 + GAPB];
  int nxt = off[a + 1];
  float acq = 0.f, ac0 = 0.f, ac1 = 0.f, ac2 = 0.f;
  const size_t NQ = (size_t)NATOMS * FD;

  for (int cb = beg; cb < pEnd; cb += 64) {
    const int nn = min(64, pEnd - cb);
    __syncthreads();
    if (t < nn * 2) ((uint4*)stage)[t] = ((const uint4*)basisS)[(size_t)cb * 2 + t];
    __syncthreads();
    if (t < nn) {
      const uint4 r0 = ((const uint4*)stage)[t * 2];
      const uint4 r1 = ((const uint4*)stage)[t * 2 + 1];
      fb[t][20] = __uint_as_float(r0.z);
      fb[t][21] = __uint_as_float(r0.w);
      fb[t][22] = __uint_as_float(r1.x);
      fb[t][23] = __uint_as_float(r1.y);
      fb[t][24] = __uint_as_float(r1.z);           // j bits
      float vp = 0.f, vc = __uint_as_float(r0.x);
      const float tc = __uint_as_float(r0.y);
      #pragma unroll
      for (int r = 0; r < NR; ++r) { fb[t][r] = vc; const float vn = tc * vc - vp; vp = vc; vc = vn; }
    }
    __syncthreads();

    // depth-2 pipeline on the 12B gather, named scalar registers
    uint pX, pY, pZ;
    {
      const uint j0 = __float_as_uint(fb[0][24]);
      const uint* xp = xmp + ((size_t)j0 * FD + t) * 3;
      pX = xp[0]; pY = xp[1]; pZ = xp[2];
    }

    for (int k = 0; k < nn; ++k) {
      const int g = cb + k;
      while (g == nxt) {                           // block-uniform flush
        out[(size_t)a * FD + t] = q[(size_t)a * FD + t] + acq;
        const size_t mi = (size_t)a * F3;
        out[NQ + mi + t]       = mu[mi + t]       + ac0;
        out[NQ + mi + 128 + t] = mu[mi + 128 + t] + ac1;
        out[NQ + mi + 256 + t] = mu[mi + 256 + t] + ac2;
        acq = ac0 = ac1 = ac2 = 0.f;
        ++a;
        nxt = (a < NATOMS) ? off[a + 1] : 0x7fffffff;
      }

      uint nX = 0u, nY = 0u, nZ = 0u;              // prefetch edge k+1
      if (k + 1 < nn) {
        const uint jj = __float_as_uint(fb[k + 1][24]);
        const uint* xp = xmp + ((size_t)jj * FD + t) * 3;
        nX = xp[0]; nY = xp[1]; nZ = xp[2];
      }

      const float* fk = fb[k];
      const float4 M = *(const float4*)(fk + 20);  // env, dir0..2 (b128 broadcast)
      v2f s0 = (v2f){0.f, 0.f}, s1 = (v2f){0.f, 0.f}, s2 = (v2f){0.f, 0.f};
      #pragma unroll
      for (int r4 = 0; r4 < 5; ++r4) {             // 5x ds_read_b128 broadcast
        const float4 bv = ((const float4*)fk)[r4];
        const v2f blo = (v2f){bv.x, bv.y};
        const v2f bhi = (v2f){bv.z, bv.w};
        s0 += blo * wf0[2 * r4]; s0 += bhi * wf0[2 * r4 + 1];
        s1 += blo * wf1[2 * r4]; s1 += bhi * wf1[2 * r4 + 1];
        s2 += blo * wf2[2 * r4]; s2 += bhi * wf2[2 * r4 + 1];
      }
      const float env = M.x;
      const float f0 = s0.x + s0.y + env * bias0;
      const float f1 = s1.x + s1.y + env * bias1;
      const float f2 = s2.x + s2.y + env * bias2;

      acq += f0 * bflo(pX);
      const float dmuR = f1 * bfhi(pX);
      const float dmm  = f2 * bflo(pY);
      ac0 += dmuR * M.y + dmm * bfhi(pY);
      ac1 += dmuR * M.z + dmm * bflo(pZ);
      ac2 += dmuR * M.w + dmm * bfhi(pZ);

      pX = nX; pY = nY; pZ = nZ;
    }
  }
  while (a < a0 + GAPB) {                          // tail / zero-edge atoms
    out[(size_t)a * FD + t] = q[(size_t)a * FD + t] + acq;
    const size_t mi = (size_t)a * F3;
    out[NQ + mi + t]       = mu[mi + t]       + ac0;
    out[NQ + mi + 128 + t] = mu[mi + 128 + t] + ac1;
    out[NQ + mi + 256 + t] = mu[mi + 256 + t] + ac2;
    acq = ac0 = ac1 = ac2 = 0.f;
    ++a;
  }
}

extern "C" void kernel_launch(void* const* d_in, const int* in_sizes, int n_in,
                              void* d_out, int out_size, void* d_ws, size_t ws_size,
                              hipStream_t stream) {
  const float* q   = (const float*)d_in[0];
  const float* mu  = (const float*)d_in[1];
  const int*   eix = (const int*)d_in[2];
  const float* ew  = (const float*)d_in[3];
  const float* W1  = (const float*)d_in[4];
  const float* b1  = (const float*)d_in[5];
  const float* W2  = (const float*)d_in[6];
  const float* b2v = (const float*)d_in[7];
  const float* Wf  = (const float*)d_in[8];
  const float* bfv = (const float*)d_in[9];
  float* out = (float*)d_out;

  // Workspace (~51.4 MB): [basisS 32B*E | xmp 12B*N*128 | off N+1 | cnt N | cursor N]
  char* w = (char*)d_ws;
  uint* basisS = (uint*)w;  w += (size_t)NEDGES * 32;
  uint* xmp    = (uint*)w;  w += (size_t)NATOMS * FD * 3 * sizeof(uint);
  int*  off    = (int*)w;   w += (size_t)(NATOMS + 1) * sizeof(int);
  int*  cnt    = (int*)w;   w += (size_t)NATOMS * sizeof(int);
  int*  cursor = (int*)w;

  hipMemsetAsync(cnt, 0, (size_t)NATOMS * sizeof(int), stream);

  hist_kernel<<<(NEDGES + 255) / 256, 256, 0, stream>>>(eix, cnt);
  scan_kernel<<<1, 512, 0, stream>>>(cnt, off, cursor);

  prep_mlp_kernel<<<PREP_BLOCKS + MLP_BLOCKS, 256, 0, stream>>>(
      eix, ew, cursor, (uint4*)basisS, q, mu, W1, b1, W2, b2v, xmp);

  gather_kernel<<<NATOMS / GAPB, 128, 0, stream>>>(q, mu, xmp, Wf, bfv,
                                                   off, basisS, out);
}

// Round 4
// 486.524 us; speedup vs baseline: 1.0402x; 1.0402x over previous
//
#include <hip/hip_runtime.h>
#include <hip/hip_bf16.h>

typedef unsigned int uint;
typedef unsigned short ushort;
typedef float v2f __attribute__((ext_vector_type(2)));

#define NATOMS 20000
#define NEDGES 640000
#define FD 128
#define F3 384
#define NR 20
#define MAPB 16     // atoms per block, MLP
#define GAPB 2      // atoms per block, gather

__device__ __forceinline__ uint f2bfu(float f) {   // f32 -> bf16 bits, RNE
  const uint u = __float_as_uint(f);
  return (u + 0x7FFFu + ((u >> 16) & 1u)) >> 16;
}
__device__ __forceinline__ float bflo(uint u) { return __uint_as_float(u << 16); }
__device__ __forceinline__ float bfhi(uint u) { return __uint_as_float(u & 0xFFFF0000u); }

// ---------------------------------------------------------------------------
// CSR build: histogram -> exclusive scan (writes off AND cursor).
// ---------------------------------------------------------------------------
__global__ __launch_bounds__(256) void hist_kernel(const int* __restrict__ eidx,
                                                   int* __restrict__ cnt) {
  const int e = blockIdx.x * 256 + threadIdx.x;
  if (e < NEDGES) atomicAdd(&cnt[eidx[e]], 1);
}

__global__ __launch_bounds__(512) void scan_kernel(const int* __restrict__ cnt,
                                                   int* __restrict__ off,
                                                   int* __restrict__ cursor) {
  __shared__ int part[512];
  const int t = threadIdx.x;
  const int CH = (NATOMS + 511) / 512;
  const int base = t * CH;
  int s = 0;
  for (int k = 0; k < CH; ++k) {
    const int idx = base + k;
    if (idx < NATOMS) s += cnt[idx];
  }
  part[t] = s;
  __syncthreads();
  if (t == 0) {
    int run = 0;
    for (int i = 0; i < 512; ++i) { const int tmp = part[i]; part[i] = run; run += tmp; }
    off[NATOMS] = run;
  }
  __syncthreads();
  int run = part[t];
  for (int k = 0; k < CH; ++k) {
    const int idx = base + k;
    if (idx < NATOMS) { off[idx] = run; cursor[idx] = run; run += cnt[idx]; }
  }
}

// ---------------------------------------------------------------------------
// Prep: 16B record {ew0, ew1, ew2, j} at destination-sorted position.
// Transcendentals moved into gather's expand phase (which has idle lanes);
// halves the scatter traffic vs the old 32B record.
// ---------------------------------------------------------------------------
__global__ __launch_bounds__(256) void prep_kernel(
    const int* __restrict__ eidx, const float* __restrict__ ew,
    int* __restrict__ cursor, uint4* __restrict__ basisS)
{
  const int e = blockIdx.x * 256 + threadIdx.x;
  if (e >= NEDGES) return;
  const int i = eidx[e];
  const int j = eidx[NEDGES + e];
  const int pos = atomicAdd(&cursor[i], 1);

  uint4 r;
  r.x = __float_as_uint(ew[(size_t)e * 3 + 0]);
  r.y = __float_as_uint(ew[(size_t)e * 3 + 1]);
  r.z = __float_as_uint(ew[(size_t)e * 3 + 2]);
  r.w = (uint)j;
  basisS[pos] = r;
}

// ---------------------------------------------------------------------------
// Phase 1: x = silu(q@W1+b1)@W2+b2; pack per (atom,feature t) a 12B record
// [x0|x1, x2|m0, m1|m2] (bf16 pairs) -> gather reads ONE dwordx3 per edge.
// K-loops quad-unrolled with float4 LDS broadcasts (4x fewer LDS instrs than
// the ds_read_b32 version, which was ~95us LDS-issue-bound).
// ---------------------------------------------------------------------------
__global__ __launch_bounds__(128) void mlp_kernel(
    const float* __restrict__ q, const float* __restrict__ mu,
    const float* __restrict__ W1, const float* __restrict__ b1,
    const float* __restrict__ W2, const float* __restrict__ b2v,
    uint* __restrict__ xmp)
{
  __shared__ float qL[MAPB][FD];
  __shared__ float hL[MAPB][FD];
  const int t = threadIdx.x;
  const int a0 = blockIdx.x * MAPB;

  #pragma unroll
  for (int a = 0; a < MAPB; ++a) qL[a][t] = q[(size_t)(a0 + a) * FD + t];
  __syncthreads();

  float hacc[MAPB];
  const float bb1 = b1[t];
  #pragma unroll
  for (int a = 0; a < MAPB; ++a) hacc[a] = bb1;
  for (int i = 0; i < FD; i += 4) {
    const float w0 = W1[(size_t)i * FD + t];
    const float w1 = W1[(size_t)(i + 1) * FD + t];
    const float w2 = W1[(size_t)(i + 2) * FD + t];
    const float w3 = W1[(size_t)(i + 3) * FD + t];
    #pragma unroll
    for (int a = 0; a < MAPB; ++a) {
      const float4 qv = *(const float4*)&qL[a][i];   // b128 broadcast
      hacc[a] += qv.x * w0 + qv.y * w1 + qv.z * w2 + qv.w * w3;
    }
  }
  #pragma unroll
  for (int a = 0; a < MAPB; ++a) hL[a][t] = hacc[a] / (1.f + __expf(-hacc[a]));
  __syncthreads();

  float x0[MAPB], x1[MAPB], x2[MAPB];
  const float c0 = b2v[t], c1 = b2v[FD + t], c2 = b2v[2 * FD + t];
  #pragma unroll
  for (int a = 0; a < MAPB; ++a) { x0[a] = c0; x1[a] = c1; x2[a] = c2; }
  for (int i = 0; i < FD; i += 4) {
    const float wa0 = W2[(size_t)i * F3 + t];
    const float wa1 = W2[(size_t)(i + 1) * F3 + t];
    const float wa2 = W2[(size_t)(i + 2) * F3 + t];
    const float wa3 = W2[(size_t)(i + 3) * F3 + t];
    const float wb0 = W2[(size_t)i * F3 + FD + t];
    const float wb1 = W2[(size_t)(i + 1) * F3 + FD + t];
    const float wb2 = W2[(size_t)(i + 2) * F3 + FD + t];
    const float wb3 = W2[(size_t)(i + 3) * F3 + FD + t];
    const float wc0 = W2[(size_t)i * F3 + 2 * FD + t];
    const float wc1 = W2[(size_t)(i + 1) * F3 + 2 * FD + t];
    const float wc2 = W2[(size_t)(i + 2) * F3 + 2 * FD + t];
    const float wc3 = W2[(size_t)(i + 3) * F3 + 2 * FD + t];
    #pragma unroll
    for (int a = 0; a < MAPB; ++a) {
      const float4 hv = *(const float4*)&hL[a][i];   // b128 broadcast
      x0[a] += hv.x * wa0 + hv.y * wa1 + hv.z * wa2 + hv.w * wa3;
      x1[a] += hv.x * wb0 + hv.y * wb1 + hv.z * wb2 + hv.w * wb3;
      x2[a] += hv.x * wc0 + hv.y * wc1 + hv.z * wc2 + hv.w * wc3;
    }
  }
  #pragma unroll
  for (int a = 0; a < MAPB; ++a) {
    const int n = a0 + a;
    const float* ma = mu + (size_t)n * F3;
    const float m0 = ma[t], m1 = ma[FD + t], m2 = ma[2 * FD + t];
    uint* dst = xmp + ((size_t)n * FD + t) * 3;
    dst[0] = f2bfu(x0[a]) | (f2bfu(x1[a]) << 16);
    dst[1] = f2bfu(x2[a]) | (f2bfu(m0) << 16);
    dst[2] = f2bfu(m1)    | (f2bfu(m2) << 16);
  }
}

// ---------------------------------------------------------------------------
// Phase 2: 128-thread blocks, GAPB=2 atoms each (contiguous CSR range).
// Thread t owns filter columns {t, 128+t, 256+t} -> the 6 b128 basis
// broadcasts per edge amortize over 3 columns. __launch_bounds__(128,3)
// keeps the 60-VGPR Wf slice resident. Expand phase now also computes
// d/sincos/env (moved out of prep). Main loop manually unrolled 2x with two
// named register sets and BRANCHLESS clamped prefetch at distance 2
// (old: depth-1 cover + per-edge exec-mask churn from `if (k+1<nn)`).
// ---------------------------------------------------------------------------
__global__ __launch_bounds__(128, 3) void gather_kernel(
    const float* __restrict__ q, const float* __restrict__ mu,
    const uint* __restrict__ xmp,
    const float* __restrict__ Wf, const float* __restrict__ bfv,
    const int* __restrict__ off, const uint4* __restrict__ basisS,
    float* __restrict__ out)
{
  __shared__ uint4 stage[64];      // raw 16B records
  __shared__ float fb[64][28];     // [0..19] basis f32, [20..23] env+dir, [24] j
  const int t = threadIdx.x;
  const int a0 = blockIdx.x * GAPB;

  v2f wf0[10], wf1[10], wf2[10];
  #pragma unroll
  for (int r = 0; r < 10; ++r) {
    wf0[r] = (v2f){Wf[(size_t)(2 * r) * F3 + t],       Wf[(size_t)(2 * r + 1) * F3 + t]};
    wf1[r] = (v2f){Wf[(size_t)(2 * r) * F3 + 128 + t], Wf[(size_t)(2 * r + 1) * F3 + 128 + t]};
    wf2[r] = (v2f){Wf[(size_t)(2 * r) * F3 + 256 + t], Wf[(size_t)(2 * r + 1) * F3 + 256 + t]};
  }
  const float bias0 = bfv[t], bias1 = bfv[128 + t], bias2 = bfv[256 + t];

  int a = a0;
  const int beg  = off[a0];
  const int pEnd = off[a0 + GAPB];
  int nxt = off[a + 1];
  float acq = 0.f, ac0 = 0.f, ac1 = 0.f, ac2 = 0.f;
  const size_t NQ = (size_t)NATOMS * FD;

  // per-edge compute on one gathered 12B record (values passed by value)
  auto edge_compute = [&](int k, uint pX, uint pY, uint pZ) {
    const float* fk = fb[k];
    const float4 M = *(const float4*)(fk + 20);  // env, dir0..2 (b128 broadcast)
    v2f s0 = (v2f){0.f, 0.f}, s1 = (v2f){0.f, 0.f}, s2 = (v2f){0.f, 0.f};
    #pragma unroll
    for (int r4 = 0; r4 < 5; ++r4) {             // 5x ds_read_b128 broadcast
      const float4 bv = ((const float4*)fk)[r4];
      const v2f blo = (v2f){bv.x, bv.y};
      const v2f bhi = (v2f){bv.z, bv.w};
      s0 += blo * wf0[2 * r4]; s0 += bhi * wf0[2 * r4 + 1];
      s1 += blo * wf1[2 * r4]; s1 += bhi * wf1[2 * r4 + 1];
      s2 += blo * wf2[2 * r4]; s2 += bhi * wf2[2 * r4 + 1];
    }
    const float env = M.x;
    const float f0 = s0.x + s0.y + env * bias0;
    const float f1 = s1.x + s1.y + env * bias1;
    const float f2 = s2.x + s2.y + env * bias2;

    acq += f0 * bflo(pX);
    const float dmuR = f1 * bfhi(pX);
    const float dmm  = f2 * bflo(pY);
    ac0 += dmuR * M.y + dmm * bfhi(pY);
    ac1 += dmuR * M.z + dmm * bflo(pZ);
    ac2 += dmuR * M.w + dmm * bfhi(pZ);
  };

  auto flush_to = [&](int g) {
    while (g == nxt) {                           // block-uniform flush
      out[(size_t)a * FD + t] = q[(size_t)a * FD + t] + acq;
      const size_t mi = (size_t)a * F3;
      out[NQ + mi + t]       = mu[mi + t]       + ac0;
      out[NQ + mi + 128 + t] = mu[mi + 128 + t] + ac1;
      out[NQ + mi + 256 + t] = mu[mi + 256 + t] + ac2;
      acq = ac0 = ac1 = ac2 = 0.f;
      ++a;
      nxt = (a < NATOMS) ? off[a + 1] : 0x7fffffff;
    }
  };

  for (int cb = beg; cb < pEnd; cb += 64) {
    const int nn = min(64, pEnd - cb);
    __syncthreads();
    if (t < nn) stage[t] = basisS[cb + t];
    __syncthreads();
    if (t < nn) {
      const uint4 r = stage[t];
      const float w0 = __uint_as_float(r.x);
      const float w1 = __uint_as_float(r.y);
      const float w2 = __uint_as_float(r.z);
      const float d = sqrtf(w0 * w0 + w1 * w1 + w2 * w2);
      const float invd = 1.f / d;
      float s1v, c1v;
      __sincosf(d * 0.628318530717958f, &s1v, &c1v);  // theta = pi*d/5
      const float env = (d < 5.f) ? 0.5f * (c1v + 1.f) : 0.f;
      fb[t][20] = env;
      fb[t][21] = w0 * invd;
      fb[t][22] = w1 * invd;
      fb[t][23] = w2 * invd;
      fb[t][24] = __uint_as_float(r.w);               // j bits
      float vp = 0.f, vc = s1v * env * invd;
      const float tc2 = 2.f * c1v;
      #pragma unroll
      for (int r2 = 0; r2 < NR; ++r2) { fb[t][r2] = vc; const float vn = tc2 * vc - vp; vp = vc; vc = vn; }
    }
    __syncthreads();

    // prologue: fill both register sets (edges 0 and 1, clamped)
    uint aX, aY, aZ, bX, bY, bZ;
    {
      const uint j0 = __float_as_uint(fb[0][24]);
      const uint* xp = xmp + ((size_t)j0 * FD + t) * 3;
      aX = xp[0]; aY = xp[1]; aZ = xp[2];
      const int k1 = (nn > 1) ? 1 : 0;
      const uint j1 = __float_as_uint(fb[k1][24]);
      const uint* yp = xmp + ((size_t)j1 * FD + t) * 3;
      bX = yp[0]; bY = yp[1]; bZ = yp[2];
    }

    int k = 0;
    while (k < nn) {
      {                                          // edge k (set A)
        flush_to(cb + k);
        const uint cX = aX, cY = aY, cZ = aZ;
        const int kp = (k + 2 < nn) ? k + 2 : nn - 1;   // branchless clamp
        const uint jj = __float_as_uint(fb[kp][24]);
        const uint* xp = xmp + ((size_t)jj * FD + t) * 3;
        aX = xp[0]; aY = xp[1]; aZ = xp[2];
        edge_compute(k, cX, cY, cZ);
      }
      if (++k >= nn) break;
      {                                          // edge k (set B)
        flush_to(cb + k);
        const uint cX = bX, cY = bY, cZ = bZ;
        const int kp = (k + 2 < nn) ? k + 2 : nn - 1;
        const uint jj = __float_as_uint(fb[kp][24]);
        const uint* xp = xmp + ((size_t)jj * FD + t) * 3;
        bX = xp[0]; bY = xp[1]; bZ = xp[2];
        edge_compute(k, cX, cY, cZ);
      }
      ++k;
    }
  }
  while (a < a0 + GAPB) {                        // tail / zero-edge atoms
    out[(size_t)a * FD + t] = q[(size_t)a * FD + t] + acq;
    const size_t mi = (size_t)a * F3;
    out[NQ + mi + t]       = mu[mi + t]       + ac0;
    out[NQ + mi + 128 + t] = mu[mi + 128 + t] + ac1;
    out[NQ + mi + 256 + t] = mu[mi + 256 + t] + ac2;
    acq = ac0 = ac1 = ac2 = 0.f;
    ++a;
  }
}

extern "C" void kernel_launch(void* const* d_in, const int* in_sizes, int n_in,
                              void* d_out, int out_size, void* d_ws, size_t ws_size,
                              hipStream_t stream) {
  const float* q   = (const float*)d_in[0];
  const float* mu  = (const float*)d_in[1];
  const int*   eix = (const int*)d_in[2];
  const float* ew  = (const float*)d_in[3];
  const float* W1  = (const float*)d_in[4];
  const float* b1  = (const float*)d_in[5];
  const float* W2  = (const float*)d_in[6];
  const float* b2v = (const float*)d_in[7];
  const float* Wf  = (const float*)d_in[8];
  const float* bfv = (const float*)d_in[9];
  float* out = (float*)d_out;

  // Workspace (~41.2 MB): [basisS 16B*E | xmp 12B*N*128 | off N+1 | cnt N | cursor N]
  char* w = (char*)d_ws;
  uint4* basisS = (uint4*)w; w += (size_t)NEDGES * 16;
  uint*  xmp    = (uint*)w;  w += (size_t)NATOMS * FD * 3 * sizeof(uint);
  int*   off    = (int*)w;   w += (size_t)(NATOMS + 1) * sizeof(int);
  int*   cnt    = (int*)w;   w += (size_t)NATOMS * sizeof(int);
  int*   cursor = (int*)w;

  hipMemsetAsync(cnt, 0, (size_t)NATOMS * sizeof(int), stream);

  hist_kernel<<<(NEDGES + 255) / 256, 256, 0, stream>>>(eix, cnt);
  scan_kernel<<<1, 512, 0, stream>>>(cnt, off, cursor);
  prep_kernel<<<(NEDGES + 255) / 256, 256, 0, stream>>>(eix, ew, cursor, basisS);

  mlp_kernel<<<NATOMS / MAPB, 128, 0, stream>>>(q, mu, W1, b1, W2, b2v, xmp);

  gather_kernel<<<NATOMS / GAPB, 128, 0, stream>>>(q, mu, xmp, Wf, bfv,
                                                   off, basisS, out);
}

// Round 5
// 386.524 us; speedup vs baseline: 1.3093x; 1.2587x over previous
//
#include <hip/hip_runtime.h>
#include <hip/hip_bf16.h>

typedef unsigned int uint;
typedef unsigned short ushort;
typedef float v2f __attribute__((ext_vector_type(2)));

#define NATOMS 20000
#define NEDGES 640000
#define FD 128
#define F3 384
#define NR 20
#define MAPB 16     // atoms per block, MLP
#define GAPB 2      // atoms per block, gather
#define CAPMAX 80   // bin capacity: mean degree 32, ~11 sigma headroom

__device__ __forceinline__ uint f2bfu(float f) {   // f32 -> bf16 bits, RNE
  const uint u = __float_as_uint(f);
  return (u + 0x7FFFu + ((u >> 16) & 1u)) >> 16;
}
__device__ __forceinline__ float bflo(uint u) { return __uint_as_float(u << 16); }
__device__ __forceinline__ float bfhi(uint u) { return __uint_as_float(u & 0xFFFF0000u); }

// ---------------------------------------------------------------------------
// Prep (ONE pass, no hist/scan): 16B record {ew0,ew1,ew2, j*1536} dropped into
// atom i's fixed-capacity bin at basisS[i*cap + pos], pos from atomicAdd.
// Replaces the 3-dispatch CSR build (hist + single-block serial scan + prep)
// and halves the device-atomic count. j premultiplied to xmp byte offset so
// gather's per-edge address calc is a single add.
// ---------------------------------------------------------------------------
__global__ __launch_bounds__(256) void prep_kernel(
    const int* __restrict__ eidx, const float* __restrict__ ew,
    int* __restrict__ cnt, uint4* __restrict__ basisS, int cap)
{
  const int e = blockIdx.x * 256 + threadIdx.x;
  if (e >= NEDGES) return;
  const int i = eidx[e];
  const int j = eidx[NEDGES + e];
  const int pos = atomicAdd(&cnt[i], 1);
  if (pos >= cap) return;                    // runtime guard (never at cap=80)

  uint4 r;
  r.x = __float_as_uint(ew[(size_t)e * 3 + 0]);
  r.y = __float_as_uint(ew[(size_t)e * 3 + 1]);
  r.z = __float_as_uint(ew[(size_t)e * 3 + 2]);
  r.w = (uint)j * (uint)(FD * 3 * 4);        // byte offset into xmp (j*1536)
  basisS[(size_t)i * cap + pos] = r;
}

// ---------------------------------------------------------------------------
// Phase 1: x = silu(q@W1+b1)@W2+b2; pack per (atom,feature t) a 12B record
// [x0|x1, x2|m0, m1|m2] (bf16 pairs) -> gather reads ONE dwordx3 per edge.
// K-loops quad-unrolled with float4 LDS broadcasts. (Unchanged from R4.)
// ---------------------------------------------------------------------------
__global__ __launch_bounds__(128) void mlp_kernel(
    const float* __restrict__ q, const float* __restrict__ mu,
    const float* __restrict__ W1, const float* __restrict__ b1,
    const float* __restrict__ W2, const float* __restrict__ b2v,
    uint* __restrict__ xmp)
{
  __shared__ float qL[MAPB][FD];
  __shared__ float hL[MAPB][FD];
  const int t = threadIdx.x;
  const int a0 = blockIdx.x * MAPB;

  #pragma unroll
  for (int a = 0; a < MAPB; ++a) qL[a][t] = q[(size_t)(a0 + a) * FD + t];
  __syncthreads();

  float hacc[MAPB];
  const float bb1 = b1[t];
  #pragma unroll
  for (int a = 0; a < MAPB; ++a) hacc[a] = bb1;
  for (int i = 0; i < FD; i += 4) {
    const float w0 = W1[(size_t)i * FD + t];
    const float w1 = W1[(size_t)(i + 1) * FD + t];
    const float w2 = W1[(size_t)(i + 2) * FD + t];
    const float w3 = W1[(size_t)(i + 3) * FD + t];
    #pragma unroll
    for (int a = 0; a < MAPB; ++a) {
      const float4 qv = *(const float4*)&qL[a][i];   // b128 broadcast
      hacc[a] += qv.x * w0 + qv.y * w1 + qv.z * w2 + qv.w * w3;
    }
  }
  #pragma unroll
  for (int a = 0; a < MAPB; ++a) hL[a][t] = hacc[a] / (1.f + __expf(-hacc[a]));
  __syncthreads();

  float x0[MAPB], x1[MAPB], x2[MAPB];
  const float c0 = b2v[t], c1 = b2v[FD + t], c2 = b2v[2 * FD + t];
  #pragma unroll
  for (int a = 0; a < MAPB; ++a) { x0[a] = c0; x1[a] = c1; x2[a] = c2; }
  for (int i = 0; i < FD; i += 4) {
    const float wa0 = W2[(size_t)i * F3 + t];
    const float wa1 = W2[(size_t)(i + 1) * F3 + t];
    const float wa2 = W2[(size_t)(i + 2) * F3 + t];
    const float wa3 = W2[(size_t)(i + 3) * F3 + t];
    const float wb0 = W2[(size_t)i * F3 + FD + t];
    const float wb1 = W2[(size_t)(i + 1) * F3 + FD + t];
    const float wb2 = W2[(size_t)(i + 2) * F3 + FD + t];
    const float wb3 = W2[(size_t)(i + 3) * F3 + FD + t];
    const float wc0 = W2[(size_t)i * F3 + 2 * FD + t];
    const float wc1 = W2[(size_t)(i + 1) * F3 + 2 * FD + t];
    const float wc2 = W2[(size_t)(i + 2) * F3 + 2 * FD + t];
    const float wc3 = W2[(size_t)(i + 3) * F3 + 2 * FD + t];
    #pragma unroll
    for (int a = 0; a < MAPB; ++a) {
      const float4 hv = *(const float4*)&hL[a][i];   // b128 broadcast
      x0[a] += hv.x * wa0 + hv.y * wa1 + hv.z * wa2 + hv.w * wa3;
      x1[a] += hv.x * wb0 + hv.y * wb1 + hv.z * wb2 + hv.w * wb3;
      x2[a] += hv.x * wc0 + hv.y * wc1 + hv.z * wc2 + hv.w * wc3;
    }
  }
  #pragma unroll
  for (int a = 0; a < MAPB; ++a) {
    const int n = a0 + a;
    const float* ma = mu + (size_t)n * F3;
    const float m0 = ma[t], m1 = ma[FD + t], m2 = ma[2 * FD + t];
    uint* dst = xmp + ((size_t)n * FD + t) * 3;
    dst[0] = f2bfu(x0[a]) | (f2bfu(x1[a]) << 16);
    dst[1] = f2bfu(x2[a]) | (f2bfu(m0) << 16);
    dst[2] = f2bfu(m1)    | (f2bfu(m2) << 16);
  }
}

// ---------------------------------------------------------------------------
// Phase 2: 128-thread blocks, GAPB=2 atoms each, per-atom fixed bins.
// Per-edge hot loop no longer has flush checks (per-atom accumulate is
// structural) and address calc is base + jbyte + t*12 (one add).
// Thread t owns filter columns {t, 128+t, 256+t}; __launch_bounds__(128,3)
// keeps the 60-VGPR Wf slice resident. 2x-unrolled loop, branchless
// distance-2 prefetch. Expand loads basisS DIRECTLY (stage-LDS hop removed).
// ---------------------------------------------------------------------------
__global__ __launch_bounds__(128, 3) void gather_kernel(
    const float* __restrict__ q, const float* __restrict__ mu,
    const uint* __restrict__ xmp,
    const float* __restrict__ Wf, const float* __restrict__ bfv,
    const int* __restrict__ cnt, const uint4* __restrict__ basisS,
    float* __restrict__ out, int cap)
{
  __shared__ float fb[64][28];     // [0..19] basis f32, [20..23] env+dir, [24] jbyte
  const int t = threadIdx.x;
  const int a0 = blockIdx.x * GAPB;
  const int tb = t * 12;
  const char* xmpC = (const char*)xmp;

  v2f wf0[10], wf1[10], wf2[10];
  #pragma unroll
  for (int r = 0; r < 10; ++r) {
    wf0[r] = (v2f){Wf[(size_t)(2 * r) * F3 + t],       Wf[(size_t)(2 * r + 1) * F3 + t]};
    wf1[r] = (v2f){Wf[(size_t)(2 * r) * F3 + 128 + t], Wf[(size_t)(2 * r + 1) * F3 + 128 + t]};
    wf2[r] = (v2f){Wf[(size_t)(2 * r) * F3 + 256 + t], Wf[(size_t)(2 * r + 1) * F3 + 256 + t]};
  }
  const float bias0 = bfv[t], bias1 = bfv[128 + t], bias2 = bfv[256 + t];

  float acq = 0.f, ac0 = 0.f, ac1 = 0.f, ac2 = 0.f;
  const size_t NQ = (size_t)NATOMS * FD;

  auto edge_compute = [&](int k, uint pX, uint pY, uint pZ) {
    const float* fk = fb[k];
    const float4 M = *(const float4*)(fk + 20);  // env, dir0..2 (b128 broadcast)
    v2f s0 = (v2f){0.f, 0.f}, s1 = (v2f){0.f, 0.f}, s2 = (v2f){0.f, 0.f};
    #pragma unroll
    for (int r4 = 0; r4 < 5; ++r4) {             // 5x ds_read_b128 broadcast
      const float4 bv = ((const float4*)fk)[r4];
      const v2f blo = (v2f){bv.x, bv.y};
      const v2f bhi = (v2f){bv.z, bv.w};
      s0 += blo * wf0[2 * r4]; s0 += bhi * wf0[2 * r4 + 1];
      s1 += blo * wf1[2 * r4]; s1 += bhi * wf1[2 * r4 + 1];
      s2 += blo * wf2[2 * r4]; s2 += bhi * wf2[2 * r4 + 1];
    }
    const float env = M.x;
    const float f0 = s0.x + s0.y + env * bias0;
    const float f1 = s1.x + s1.y + env * bias1;
    const float f2 = s2.x + s2.y + env * bias2;

    acq += f0 * bflo(pX);
    const float dmuR = f1 * bfhi(pX);
    const float dmm  = f2 * bflo(pY);
    ac0 += dmuR * M.y + dmm * bfhi(pY);
    ac1 += dmuR * M.z + dmm * bflo(pZ);
    ac2 += dmuR * M.w + dmm * bfhi(pZ);
  };

  for (int aa = 0; aa < GAPB; ++aa) {
    const int a = a0 + aa;
    int deg = cnt[a];
    if (deg > cap) deg = cap;                    // guard (never at cap=80)
    const uint4* bin = basisS + (size_t)a * cap;

    for (int cb = 0; cb < deg; cb += 64) {
      const int nn = min(64, deg - cb);
      __syncthreads();                           // fb reuse hazard
      if (t < nn) {
        const uint4 r = bin[cb + t];             // direct 16B coalesced load
        const float w0 = __uint_as_float(r.x);
        const float w1 = __uint_as_float(r.y);
        const float w2 = __uint_as_float(r.z);
        const float d = sqrtf(w0 * w0 + w1 * w1 + w2 * w2);
        const float invd = 1.f / d;
        float s1v, c1v;
        __sincosf(d * 0.628318530717958f, &s1v, &c1v);  // theta = pi*d/5
        const float env = (d < 5.f) ? 0.5f * (c1v + 1.f) : 0.f;
        fb[t][20] = env;
        fb[t][21] = w0 * invd;
        fb[t][22] = w1 * invd;
        fb[t][23] = w2 * invd;
        fb[t][24] = __uint_as_float(r.w);               // jbyte bits
        float vp = 0.f, vc = s1v * env * invd;
        const float tc2 = 2.f * c1v;
        #pragma unroll
        for (int r2 = 0; r2 < NR; ++r2) { fb[t][r2] = vc; const float vn = tc2 * vc - vp; vp = vc; vc = vn; }
      }
      __syncthreads();

      // prologue: fill both register sets (edges 0 and 1, clamped)
      uint aX, aY, aZ, bX, bY, bZ;
      {
        const uint j0 = __float_as_uint(fb[0][24]);
        const uint* xp = (const uint*)(xmpC + j0 + tb);
        aX = xp[0]; aY = xp[1]; aZ = xp[2];
        const int k1 = (nn > 1) ? 1 : 0;
        const uint j1 = __float_as_uint(fb[k1][24]);
        const uint* yp = (const uint*)(xmpC + j1 + tb);
        bX = yp[0]; bY = yp[1]; bZ = yp[2];
      }

      int k = 0;
      while (k < nn) {
        {                                        // edge k (set A)
          const uint cX = aX, cY = aY, cZ = aZ;
          const int kp = (k + 2 < nn) ? k + 2 : nn - 1;   // branchless clamp
          const uint jj = __float_as_uint(fb[kp][24]);
          const uint* xp = (const uint*)(xmpC + jj + tb);
          aX = xp[0]; aY = xp[1]; aZ = xp[2];
          edge_compute(k, cX, cY, cZ);
        }
        if (++k >= nn) break;
        {                                        // edge k (set B)
          const uint cX = bX, cY = bY, cZ = bZ;
          const int kp = (k + 2 < nn) ? k + 2 : nn - 1;
          const uint jj = __float_as_uint(fb[kp][24]);
          const uint* xp = (const uint*)(xmpC + jj + tb);
          bX = xp[0]; bY = xp[1]; bZ = xp[2];
          edge_compute(k, cX, cY, cZ);
        }
        ++k;
      }
    }

    // unconditional per-atom flush (handles deg==0 too)
    out[(size_t)a * FD + t] = q[(size_t)a * FD + t] + acq;
    const size_t mi = (size_t)a * F3;
    out[NQ + mi + t]       = mu[mi + t]       + ac0;
    out[NQ + mi + 128 + t] = mu[mi + 128 + t] + ac1;
    out[NQ + mi + 256 + t] = mu[mi + 256 + t] + ac2;
    acq = ac0 = ac1 = ac2 = 0.f;
  }
}

extern "C" void kernel_launch(void* const* d_in, const int* in_sizes, int n_in,
                              void* d_out, int out_size, void* d_ws, size_t ws_size,
                              hipStream_t stream) {
  const float* q   = (const float*)d_in[0];
  const float* mu  = (const float*)d_in[1];
  const int*   eix = (const int*)d_in[2];
  const float* ew  = (const float*)d_in[3];
  const float* W1  = (const float*)d_in[4];
  const float* b1  = (const float*)d_in[5];
  const float* W2  = (const float*)d_in[6];
  const float* b2v = (const float*)d_in[7];
  const float* Wf  = (const float*)d_in[8];
  const float* bfv = (const float*)d_in[9];
  float* out = (float*)d_out;

  // Workspace: [xmp 12B*N*128 (30.7MB) | cnt 80KB | basisS 16B*N*cap (25.6MB @80)]
  char* w = (char*)d_ws;
  uint* xmp = (uint*)w;  w += (size_t)NATOMS * FD * 3 * sizeof(uint);
  int*  cnt = (int*)w;   w += (size_t)NATOMS * sizeof(int);
  uint4* basisS = (uint4*)w;

  const size_t used = (size_t)NATOMS * FD * 3 * sizeof(uint) + (size_t)NATOMS * sizeof(int);
  int cap = CAPMAX;
  if (ws_size > used) {
    const size_t mx = (ws_size - used) / ((size_t)NATOMS * 16);
    if ((size_t)cap > mx) cap = (int)mx;       // degrade gracefully if ws tight
  }

  hipMemsetAsync(cnt, 0, (size_t)NATOMS * sizeof(int), stream);

  prep_kernel<<<(NEDGES + 255) / 256, 256, 0, stream>>>(eix, ew, cnt, basisS, cap);

  mlp_kernel<<<NATOMS / MAPB, 128, 0, stream>>>(q, mu, W1, b1, W2, b2v, xmp);

  gather_kernel<<<NATOMS / GAPB, 128, 0, stream>>>(q, mu, xmp, Wf, bfv,
                                                   cnt, basisS, out, cap);
}